// Round 1
// baseline (292.267 us; speedup 1.0000x reference)
//
#include <hip/hip_runtime.h>
#include <math.h>

#define Bn 4
#define Nn 512
#define Dn 64
#define Hn 8
#define ES 516  // ehat_s row stride (516 % 32 == 4 -> distinct banks across h)

// ---------------- Kernel 1: QKV projection -------------------------------
// Q/K/V[row][d] = sum_k n[row][k] * W[k][d]; row = b*N+q, layout (B,N,D).
__global__ __launch_bounds__(64) void qkv_kernel(
    const float* __restrict__ nin, const float* __restrict__ Wq,
    const float* __restrict__ Wk, const float* __restrict__ Wv,
    float* __restrict__ Qw, float* __restrict__ Kw, float* __restrict__ Vw)
{
    const int row = blockIdx.x;   // 0 .. B*N-1
    const int d = threadIdx.x;    // 0 .. 63
    __shared__ float nrow[Dn];
    nrow[d] = nin[row * Dn + d];
    __syncthreads();
    float aq = 0.f, ak = 0.f, av = 0.f;
#pragma unroll
    for (int k = 0; k < Dn; ++k) {
        const float nv = nrow[k];
        aq = fmaf(nv, Wq[k * Dn + d], aq);
        ak = fmaf(nv, Wk[k * Dn + d], ak);
        av = fmaf(nv, Wv[k * Dn + d], av);
    }
    Qw[row * Dn + d] = aq;
    Kw[row * Dn + d] = ak;
    Vw[row * Dn + d] = av;
}

// ---------------- Kernel 2: fused edge-bias attention ---------------------
// One block per (b,q). Phase 1: stream e rows (lane-owns-row), compute
// Eb/G/A/Ehat, write e_out immediately, stash Ehat in LDS, accumulate G-sums.
// Phase 2: softmax over m (no max-subtract; |Ehat| <= ~8 so exp is safe),
// P@V, dyn_centrality scaling, @Wo -> n_out.
__global__ __launch_bounds__(256) void fused_kernel(
    const float* __restrict__ e,
    const float* __restrict__ Qw, const float* __restrict__ Kw,
    const float* __restrict__ Vw,
    const float* __restrict__ WeG, const float* __restrict__ WgG,
    const float* __restrict__ OeG, const float* __restrict__ WoG,
    float* __restrict__ nout, float* __restrict__ eout)
{
    const int bq = blockIdx.x;      // b*N + q
    const int b  = bq >> 9;         // N = 512
    const int t  = threadIdx.x;     // 0..255
    const int w  = t >> 6;          // wave 0..3
    const int l  = t & 63;          // lane 0..63

    __shared__ float ehat_s[Hn][ES];
    __shared__ __align__(16) float we_s[Hn][Dn];
    __shared__ __align__(16) float wg_s[Hn][Dn];
    __shared__ __align__(16) float oe_s[Hn][Dn];
    __shared__ __align__(16) float q_s[Dn];
    __shared__ float smb[4][Hn];
    __shared__ float gsb[4][Hn];
    __shared__ float accb[4][Dn];
    __shared__ float vo_s[Dn];

    // Stage weights. We/Wg are (D,H): transpose to [h][d]. Oe is (H,D): copy.
    for (int i = t; i < Dn * Hn; i += 256) {
        const int d = i >> 3, h = i & 7;
        we_s[h][d] = WeG[i];
        wg_s[h][d] = WgG[i];
        ((float*)oe_s)[i] = OeG[i];
    }
    if (t < Dn) q_s[t] = Qw[bq * Dn + t];
    __syncthreads();

    const float qscale = 0.35355339059327373f;  // 1/sqrt(8)
    float gpart[Hn];
#pragma unroll
    for (int h = 0; h < Hn; ++h) gpart[h] = 0.f;

    // ---------------- Phase 1: two rounds, m = rd*256 + t ----------------
    for (int rd = 0; rd < 2; ++rd) {
        const int m = rd * 256 + t;

        // e row -> registers (16 x float4)
        const float4* ep = (const float4*)(e + ((size_t)bq * Nn + m) * Dn);
        float4 ev[16];
#pragma unroll
        for (int j = 0; j < 16; ++j) ev[j] = ep[j];

        // Eb/G dots: weights broadcast from LDS (wave-uniform address)
        float eb[Hn], gg[Hn];
#pragma unroll
        for (int h = 0; h < Hn; ++h) { eb[h] = 0.f; gg[h] = 0.f; }
#pragma unroll
        for (int d4 = 0; d4 < 16; ++d4) {
            const float4 e4 = ev[d4];
#pragma unroll
            for (int h = 0; h < Hn; ++h) {
                const float4 w4 = ((const float4*)we_s[h])[d4];
                const float4 g4 = ((const float4*)wg_s[h])[d4];
                eb[h] = fmaf(e4.x, w4.x, fmaf(e4.y, w4.y,
                         fmaf(e4.z, w4.z, fmaf(e4.w, w4.w, eb[h]))));
                gg[h] = fmaf(e4.x, g4.x, fmaf(e4.y, g4.y,
                         fmaf(e4.z, g4.z, fmaf(e4.w, g4.w, gg[h]))));
            }
        }

        // A[h] = clip(Q.K * scale); Ehat = A + Eb; sigmoid(G) partial sums
        const float4* kp = (const float4*)(Kw + ((size_t)b * Nn + m) * Dn);
        const float4* q4 = (const float4*)q_s;
        float ehat[Hn];
#pragma unroll
        for (int h = 0; h < Hn; ++h) {
            const float4 k0 = kp[2 * h], k1 = kp[2 * h + 1];
            const float4 p0 = q4[2 * h], p1 = q4[2 * h + 1];
            float a = k0.x * p0.x + k0.y * p0.y + k0.z * p0.z + k0.w * p0.w
                    + k1.x * p1.x + k1.y * p1.y + k1.z * p1.z + k1.w * p1.w;
            a *= qscale;
            a = fminf(fmaxf(a, -5.f), 5.f);
            const float eh = a + eb[h];
            ehat[h] = eh;
            ehat_s[h][m] = eh;
            gpart[h] += 1.f / (1.f + __expf(-gg[h]));
        }

        // e_out row = Ehat(1x8) @ Oe(8x64), written immediately
        float* eo = eout + ((size_t)bq * Nn + m) * Dn;
#pragma unroll
        for (int d4 = 0; d4 < 16; ++d4) {
            float4 o; o.x = o.y = o.z = o.w = 0.f;
#pragma unroll
            for (int h = 0; h < Hn; ++h) {
                const float4 w4 = ((const float4*)oe_s[h])[d4];
                const float s = ehat[h];
                o.x = fmaf(s, w4.x, o.x);
                o.y = fmaf(s, w4.y, o.y);
                o.z = fmaf(s, w4.z, o.z);
                o.w = fmaf(s, w4.w, o.w);
            }
            ((float4*)eo)[d4] = o;
        }
    }
    __syncthreads();

    // ---------------- Phase 2: softmax + P@V ------------------------------
    const int h = l >> 3, dk = l & 7;  (void)dk;
    float sm = 0.f, acc = 0.f;
    const float* vb = Vw + (size_t)b * Nn * Dn;
#pragma unroll 8
    for (int i = 0; i < 128; ++i) {
        const int m = w * 128 + i;
        const float p = __expf(ehat_s[h][m]);
        sm += p;
        acc = fmaf(p, vb[m * Dn + l], acc);
    }

    // reduce gpart across the wave (each lane covered distinct m's)
#pragma unroll
    for (int hh = 0; hh < Hn; ++hh) {
        float v = gpart[hh];
#pragma unroll
        for (int off = 32; off > 0; off >>= 1) v += __shfl_xor(v, off, 64);
        if (l == 0) gsb[w][hh] = v;
    }
    if ((l & 7) == 0) smb[w][h] = sm;
    accb[w][l] = acc;
    __syncthreads();

    if (w == 0) {
        float S = 0.f, O = 0.f, G = 0.f;
#pragma unroll
        for (int ww = 0; ww < 4; ++ww) {
            S += smb[ww][h];
            O += accb[ww][l];
            G += gsb[ww][h];
        }
        vo_s[l] = (O / S) * log1pf(G);
    }
    __syncthreads();

    if (w == 0) {
        float a2 = 0.f;
#pragma unroll
        for (int k = 0; k < Dn; ++k)
            a2 = fmaf(vo_s[k], WoG[k * Dn + l], a2);
        nout[(size_t)bq * Dn + l] = a2;
    }
}

// ---------------- Host launcher -------------------------------------------
extern "C" void kernel_launch(void* const* d_in, const int* in_sizes, int n_in,
                              void* d_out, int out_size, void* d_ws, size_t ws_size,
                              hipStream_t stream)
{
    (void)in_sizes; (void)n_in; (void)out_size; (void)ws_size;
    const float* nin = (const float*)d_in[0];
    const float* e   = (const float*)d_in[1];
    const float* Wq  = (const float*)d_in[2];
    const float* Wk  = (const float*)d_in[3];
    const float* Wv  = (const float*)d_in[4];
    const float* Wo  = (const float*)d_in[5];
    const float* Wg  = (const float*)d_in[6];
    const float* We  = (const float*)d_in[7];
    const float* Oe  = (const float*)d_in[8];

    float* Qw = (float*)d_ws;                 // B*N*D floats
    float* Kw = Qw + Bn * Nn * Dn;
    float* Vw = Kw + Bn * Nn * Dn;

    float* nout = (float*)d_out;              // B*N*D floats
    float* eout = nout + Bn * Nn * Dn;        // B*N*N*D floats

    qkv_kernel<<<Bn * Nn, 64, 0, stream>>>(nin, Wq, Wk, Wv, Qw, Kw, Vw);
    fused_kernel<<<Bn * Nn, 256, 0, stream>>>(e, Qw, Kw, Vw, We, Wg, Oe, Wo,
                                              nout, eout);
}